// Round 5
// baseline (1081.418 us; speedup 1.0000x reference)
//
#include <hip/hip_runtime.h>
#include <stdint.h>

typedef unsigned short u16;
typedef unsigned int u32;
typedef __attribute__((ext_vector_type(8))) __bf16 bf16x8;
typedef __attribute__((ext_vector_type(4))) float f32x4;
typedef __attribute__((ext_vector_type(4))) u32 u32x4;
typedef __attribute__((ext_vector_type(2))) u32 u32x2;

#define DEV __device__ __forceinline__

constexpr int V = 5000, D = 300, H = 256, BB = 16, T = 512;
constexpr int M = BB * T;      // 8192
constexpr int DP = 320;        // D padded to 20*16
constexpr int KP = 5024;       // V padded to mult of 32 (E_b k-dim)
constexpr int G4 = 1024;       // 4H
constexpr int NPAD = 5120;     // V padded to 20*256 (out n-dim)

// workspace layout (bytes, all 256-aligned). total ~38.6 MB.
constexpr size_t OFF_EB    = 0;                                   // bf16 [DP][KP]
constexpr size_t OFF_WXB   = OFF_EB    + (size_t)DP * KP * 2;     // bf16 [G4][DP]  (f,g,i,o)
constexpr size_t OFF_UHB   = OFF_WXB   + (size_t)G4 * DP * 2;     // bf16 [G4][H]
constexpr size_t OFF_WOUTB = OFF_UHB   + (size_t)G4 * H * 2;      // bf16 [NPAD][H]
constexpr size_t OFF_GATES = OFF_WOUTB + (size_t)NPAD * H * 2;    // bf16 [T][B][256][4g]
constexpr size_t OFF_GALL  = OFF_GATES + (size_t)T * BB * G4 * 2; // bf16 [M][H], m=b*T+t
constexpr size_t OFF_EMB   = OFF_GALL  + (size_t)M * H * 2;       // f32  [M][DP]
constexpr size_t OFF_HEXF  = OFF_EMB   + (size_t)M * DP * 4;      // FAST exch [8g][2r][2par][64c]x16B
constexpr size_t OFF_HEXS  = OFF_HEXF  + 32768;                   // SAFE exch, same shape

DEV u16 f2bf(float f) {
  u32 i = __builtin_bit_cast(u32, f);
  return (u16)((i + 0x7FFFu + ((i >> 16) & 1u)) >> 16);
}
DEV float bf2f(u16 u) { return __builtin_bit_cast(float, (u32)u << 16); }
DEV u32 pk2(float a, float b) { return (u32)f2bf(a) | ((u32)f2bf(b) << 16); }
DEV f32x4 MFMA(u32x4 a, u32x4 b, f32x4 c) {
  return __builtin_amdgcn_mfma_f32_16x16x32_bf16(
      __builtin_bit_cast(bf16x8, a), __builtin_bit_cast(bf16x8, b), c, 0, 0, 0);
}
DEV float sigm(float x) { return 1.f / (1.f + __expf(-x)); }
DEV float tanh_s(float x) { float e = __expf(2.f * x); return 1.f - 2.f / (e + 1.f); }

// --- 16B exchange ops. fast = sc0 (per-XCD L2 coherent); safe = sc0 sc1 (LLC, cross-XCD). ---
DEV u32x4 ld16f(const void* p) {
  u32x4 v;
  asm volatile("global_load_dwordx4 %0, %1, off sc0" : "=v"(v) : "v"(p));
  return v;
}
DEV u32x4 ld16s(const void* p) {
  u32x4 v;
  asm volatile("global_load_dwordx4 %0, %1, off sc0 sc1" : "=v"(v) : "v"(p));
  return v;
}
DEV u32x4 spin16s(const void* p, u32 want) {
  u32x4 v;
  do {
    asm volatile("global_load_dwordx4 %0, %1, off sc0 sc1\n\ts_waitcnt vmcnt(0)"
                 : "=v"(v) : "v"(p) : "memory");
  } while (v[3] != want);
  return v;
}
DEV void st16f(void* p, u32x4 v) {
  asm volatile("global_store_dwordx4 %0, %1, off sc0" :: "v"(p), "v"(v) : "memory");
}
DEV void st16s(void* p, u32x4 v) {
  asm volatile("global_store_dwordx4 %0, %1, off sc0 sc1" :: "v"(p), "v"(v) : "memory");
}
// raw barrier with LDS visibility; does NOT drain vmcnt
DEV void bar_lds() {
  asm volatile("s_waitcnt lgkmcnt(0)" ::: "memory");
  __builtin_amdgcn_sched_barrier(0);
  __builtin_amdgcn_s_barrier();
  __builtin_amdgcn_sched_barrier(0);
}
DEV char* exch_addr(char* exch, int g, int r, int par, int c) {
  return exch + (size_t)(((((g * 2 + r) * 2 + par) * 64) + c) << 4);
}

// ---------------- K0: weight prep (fp32 -> padded bf16), exch tag init (both buffers)
__global__ __launch_bounds__(256) void k_prep(
    const float* __restrict__ E, const float* __restrict__ Wf, const float* __restrict__ Wg,
    const float* __restrict__ Wi, const float* __restrict__ Wo, const float* __restrict__ Uf,
    const float* __restrict__ Ug, const float* __restrict__ Ui, const float* __restrict__ Uo,
    const float* __restrict__ Wout, char* __restrict__ ws) {
  u16* Eb = (u16*)(ws + OFF_EB);
  u16* Wxb = (u16*)(ws + OFF_WXB);
  u16* Uhb = (u16*)(ws + OFF_UHB);
  u16* Wob = (u16*)(ws + OFF_WOUTB);

  const int NE = DP * KP, NW = G4 * DP, NU = G4 * H, NWO = NPAD * H;
  const int total = NE + NW + NU + NWO + 4096;
  for (int i = blockIdx.x * blockDim.x + threadIdx.x; i < total; i += gridDim.x * blockDim.x) {
    int j = i;
    if (j < NE) {
      int nn = j / KP, k = j % KP;
      Eb[j] = f2bf((nn < D && k < V) ? E[(size_t)nn * V + k] : 0.f);
      continue;
    }
    j -= NE;
    if (j < NW) {
      int r = j / DP, k = j % DP;
      const float* Wp = (r < 256) ? Wf : (r < 512) ? Wg : (r < 768) ? Wi : Wo;
      Wxb[j] = f2bf((k < D) ? Wp[(size_t)(r & 255) * D + k] : 0.f);
      continue;
    }
    j -= NW;
    if (j < NU) {
      int r = j / H, k = j % H;
      const float* Up = (r < 256) ? Uf : (r < 512) ? Ug : (r < 768) ? Ui : Uo;
      Uhb[j] = f2bf(Up[(size_t)(r & 255) * H + k]);
      continue;
    }
    j -= NU;
    if (j < NWO) {
      int nn = j / H, k = j % H;
      Wob[j] = f2bf((nn < V) ? Wout[(size_t)nn * H + k] : 0.f);
      continue;
    }
    j -= NWO;
    if (j < 4096) {  // fast (0..2047) + safe (2048..4095) chunks: invalid tag
      u32x4 v; v[0] = 0u; v[1] = 0u; v[2] = 0u; v[3] = 0xFFFFFFFFu;
      *(u32x4*)(ws + OFF_HEXF + ((size_t)j << 4)) = v;
      continue;
    }
  }
}

// ---------------- K1: emb = x @ E^T   (M=8192, N=DP=320, K=V; BM=32, grid=256)
__global__ __launch_bounds__(256) void k_emb(const float* __restrict__ x, char* __restrict__ ws) {
  const u16* Eb = (const u16*)(ws + OFF_EB);
  float* emb = (float*)(ws + OFF_EMB);
  __shared__ __align__(16) u16 As[32 * 40];
  __shared__ __align__(16) u16 Bs[320 * 40];

  const int tid = threadIdx.x;
  const int m0 = blockIdx.x * 32;
  const int lane = tid & 63, wv = tid >> 6;
  const int l15 = lane & 15, lc = lane >> 4;
  const int mt = wv & 1, ntb = (wv >> 1) * 10;

  f32x4 acc[10];
#pragma unroll
  for (int j = 0; j < 10; j++) acc[j] = (f32x4){0.f, 0.f, 0.f, 0.f};

  const int ar = tid >> 3, ak = (tid & 7) * 4;

  f32x4 xv0, xv1;
  u32x4 ev0[5], ev1[5];

#define EMB_ISSUE(SFX, KS)                                                        \
  do {                                                                            \
    int k0_ = (KS) * 32;                                                          \
    {                                                                             \
      size_t base_ = (size_t)(m0 + ar) * V + k0_ + ak;                            \
      if (k0_ + ak + 3 < V) {                                                     \
        xv##SFX = *(const f32x4*)(x + base_);                                     \
      } else {                                                                    \
        f32x4 t_;                                                                 \
        t_[0] = (k0_ + ak + 0 < V) ? x[base_ + 0] : 0.f;                          \
        t_[1] = (k0_ + ak + 1 < V) ? x[base_ + 1] : 0.f;                          \
        t_[2] = (k0_ + ak + 2 < V) ? x[base_ + 2] : 0.f;                          \
        t_[3] = (k0_ + ak + 3 < V) ? x[base_ + 3] : 0.f;                          \
        xv##SFX = t_;                                                             \
      }                                                                           \
    }                                                                             \
    _Pragma("unroll") for (int j_ = 0; j_ < 5; j_++) {                            \
      int cc_ = tid + 256 * j_;                                                   \
      int n_ = cc_ >> 2, ko_ = (cc_ & 3) * 8;                                     \
      ev##SFX[j_] = *(const u32x4*)(Eb + (size_t)n_ * KP + k0_ + ko_);            \
    }                                                                             \
  } while (0)

#define EMB_WRITE(SFX)                                                            \
  do {                                                                            \
    union { u16 u[4]; u32x2 v; } ua_;                                             \
    ua_.u[0] = f2bf(xv##SFX[0]); ua_.u[1] = f2bf(xv##SFX[1]);                     \
    ua_.u[2] = f2bf(xv##SFX[2]); ua_.u[3] = f2bf(xv##SFX[3]);                     \
    *(u32x2*)&As[ar * 40 + ak] = ua_.v;                                           \
    _Pragma("unroll") for (int j_ = 0; j_ < 5; j_++) {                            \
      int cc_ = tid + 256 * j_;                                                   \
      int n_ = cc_ >> 2, ko_ = (cc_ & 3) * 8;                                     \
      *(u32x4*)&Bs[n_ * 40 + ko_] = ev##SFX[j_];                                  \
    }                                                                             \
  } while (0)

  auto emb_compute = [&]() {
    u32x4 a = *(const u32x4*)&As[(mt * 16 + l15) * 40 + lc * 8];
#pragma unroll
    for (int j = 0; j < 10; j++) {
      u32x4 b = *(const u32x4*)&Bs[((ntb + j) * 16 + l15) * 40 + lc * 8];
      acc[j] = MFMA(a, b, acc[j]);
    }
  };

  constexpr int NK = 157;  // ceil(5000/32)
  EMB_ISSUE(0, 0);
  EMB_ISSUE(1, 1);
  for (int ks = 0; ks < NK; ks += 2) {
    __syncthreads();
    EMB_WRITE(0);
    if (ks + 2 < NK) EMB_ISSUE(0, ks + 2);
    __syncthreads();
    emb_compute();
    if (ks + 1 < NK) {
      __syncthreads();
      EMB_WRITE(1);
      if (ks + 3 < NK) EMB_ISSUE(1, ks + 3);
      __syncthreads();
      emb_compute();
    }
  }
#pragma unroll
  for (int j = 0; j < 10; j++) {
    int nn = (ntb + j) * 16 + l15;
    int mrow = m0 + mt * 16 + lc * 4;
#pragma unroll
    for (int r = 0; r < 4; r++) emb[(size_t)(mrow + r) * DP + nn] = acc[j][r];
  }
#undef EMB_ISSUE
#undef EMB_WRITE
}

// ---------------- K2: gates = emb @ Wx^T -> bf16 [t][b][n][4]  (BM=64,BN=256,K=DP)
__global__ __launch_bounds__(256) void k_gates(char* __restrict__ ws) {
  const float* emb = (const float*)(ws + OFF_EMB);
  const u16* Wxb = (const u16*)(ws + OFF_WXB);
  u16* gates = (u16*)(ws + OFF_GATES);
  __shared__ __align__(16) u16 As[64 * 40];
  __shared__ __align__(16) u16 Bs[256 * 40];

  const int tid = threadIdx.x;
  const int blk = blockIdx.x;
  const int m0 = (blk >> 2) * 64, n0 = (blk & 3) * 256;
  const int lane = tid & 63, wv = tid >> 6;
  const int l15 = lane & 15, lc = lane >> 4;

  f32x4 acc[16];
#pragma unroll
  for (int j = 0; j < 16; j++) acc[j] = (f32x4){0.f, 0.f, 0.f, 0.f};

  f32x4 av0[2], av1[2];
  u32x4 bv0[4], bv1[4];

#define GT_ISSUE(SFX, KS)                                                         \
  do {                                                                            \
    int k0_ = (KS) * 32;                                                          \
    _Pragma("unroll") for (int j_ = 0; j_ < 2; j_++) {                            \
      int c_ = tid + 256 * j_;                                                    \
      int r_ = c_ >> 3, ko_ = (c_ & 7) * 4;                                       \
      av##SFX[j_] = *(const f32x4*)(emb + (size_t)(m0 + r_) * DP + k0_ + ko_);    \
    }                                                                             \
    _Pragma("unroll") for (int j_ = 0; j_ < 4; j_++) {                            \
      int c_ = tid + 256 * j_;                                                    \
      int n_ = c_ >> 2, ko_ = (c_ & 3) * 8;                                       \
      bv##SFX[j_] = *(const u32x4*)(Wxb + (size_t)(n0 + n_) * DP + k0_ + ko_);    \
    }                                                                             \
  } while (0)

#define GT_WRITE(SFX)                                                             \
  do {                                                                            \
    _Pragma("unroll") for (int j_ = 0; j_ < 2; j_++) {                            \
      int c_ = tid + 256 * j_;                                                    \
      int r_ = c_ >> 3, ko_ = (c_ & 7) * 4;                                       \
      union { u16 u[4]; u32x2 v; } ua_;                                           \
      ua_.u[0] = f2bf(av##SFX[j_][0]); ua_.u[1] = f2bf(av##SFX[j_][1]);           \
      ua_.u[2] = f2bf(av##SFX[j_][2]); ua_.u[3] = f2bf(av##SFX[j_][3]);           \
      *(u32x2*)&As[r_ * 40 + ko_] = ua_.v;                                        \
    }                                                                             \
    _Pragma("unroll") for (int j_ = 0; j_ < 4; j_++) {                            \
      int c_ = tid + 256 * j_;                                                    \
      int n_ = c_ >> 2, ko_ = (c_ & 3) * 8;                                       \
      *(u32x4*)&Bs[n_ * 40 + ko_] = bv##SFX[j_];                                  \
    }                                                                             \
  } while (0)

  auto gt_compute = [&]() {
    u32x4 a = *(const u32x4*)&As[(wv * 16 + l15) * 40 + lc * 8];
#pragma unroll
    for (int nt = 0; nt < 16; nt++) {
      u32x4 b = *(const u32x4*)&Bs[(nt * 16 + l15) * 40 + lc * 8];
      acc[nt] = MFMA(a, b, acc[nt]);
    }
  };

  constexpr int NK = 10;  // DP/32
  GT_ISSUE(0, 0);
  GT_ISSUE(1, 1);
  for (int ks = 0; ks < NK; ks += 2) {
    __syncthreads();
    GT_WRITE(0);
    if (ks + 2 < NK) GT_ISSUE(0, ks + 2);
    __syncthreads();
    gt_compute();
    __syncthreads();
    GT_WRITE(1);
    if (ks + 3 < NK) GT_ISSUE(1, ks + 3);
    __syncthreads();
    gt_compute();
  }
#pragma unroll
  for (int nt = 0; nt < 16; nt++) {
#pragma unroll
    for (int r = 0; r < 4; r++) {
      int m = m0 + wv * 16 + lc * 4 + r;     // m = b*T + t
      int col = n0 + nt * 16 + l15;          // 0..1023
      int q = col >> 8, nn = col & 255;
      gates[(((size_t)(m & (T - 1)) * 16 + (m >> 9)) * 256 + nn) * 4 + q] = f2bf(acc[nt][r]);
    }
  }
#undef GT_ISSUE
#undef GT_WRITE
}

// ---------------- K3: recurrent scan, batch-partitioned pairs, dual-scope exchange.
// 16 WGs: pair (w, w^8) handles batches {2g,2g+1}, g=w&7; role r=w>>3 owns n in [128r,128r+128).
// Producer writes its h-half chunk to BOTH a fast (sc0, per-XCD L2) and a safe (sc0 sc1, LLC)
// buffer. Consumer spins fast with a bounded budget, then falls back to the guaranteed safe
// path and collapses to safe-only mode. Deadlock-free regardless of WG->XCD placement.
__global__ __launch_bounds__(512) void k_scan(const float* __restrict__ hidden,
                                              const float* __restrict__ ctx,
                                              char* __restrict__ ws) {
  const u16* Uhb = (const u16*)(ws + OFF_UHB);
  const u16* gates = (const u16*)(ws + OFF_GATES);
  u16* gall = (u16*)(ws + OFF_GALL);
  char* exchF = ws + OFF_HEXF;
  char* exchS = ws + OFF_HEXS;

  __shared__ __align__(16) u16 hb[2 * 16 * 256];  // [par][16 rows][256 k] bf16, XOR-swizzled
  __shared__ float zl[128 * 9];                   // [n_loc][gate*2 + b]

  const int w = blockIdx.x;
  const int g = w & 7, role = w >> 3;
  const int tid = threadIdx.x;
  const int lane = tid & 63, wv = tid >> 6;
  const int l15 = lane & 15, lc = lane >> 4;
  const int q = wv >> 1, sub = wv & 1;

  // Uh fragments: rows q*256 + role*128 + sub*64 + rb*16 + l15, k = kt*32 + lc*8
  u32x4 uh[4][8];
#pragma unroll
  for (int rb = 0; rb < 4; rb++)
#pragma unroll
    for (int kt = 0; kt < 8; kt++)
      uh[rb][kt] = *(const u32x4*)(
          Uhb + (size_t)(q * 256 + role * 128 + sub * 64 + rb * 16 + l15) * H + kt * 32 + lc * 8);

  // zero hbuf (both parities; rows 2..15 stay zero = MFMA B padding cols)
  for (int i = tid; i < 4096; i += 512) ((u32*)hb)[i] = 0u;
  __syncthreads();

  // h(0) into hbuf[par=0] rows 0,1 (read from `hidden` directly; batch-independent)
  if (tid < 256) {
    const int b = (tid >> 7) & 1, n_loc = tid & 127;
    const int n_glob = role * 128 + n_loc;
    hb[b * 256 + (n_glob ^ ((b & 7) << 3))] = f2bf(hidden[n_glob]);
  } else if (tid < 320) {
    const int s = tid - 256;
    const int pb = s >> 5;
    const int pn0 = (role ^ 1) * 128 + (s & 31) * 4;
#pragma unroll
    for (int jj = 0; jj < 4; jj++)
      hb[pb * 256 + ((pn0 + jj) ^ ((pb & 7) << 3))] = f2bf(hidden[pn0 + jj]);
  }
  __syncthreads();

  const bool is_ew = tid < 256;
  const bool is_st = (tid >= 256) && (tid < 320);

  // elementwise ids
  const int b = (tid >> 7) & 1;
  const int n_loc = tid & 127;
  const int n_glob = role * 128 + n_loc;
  const int b_glob = g * 2 + b;

  // staging ids (64 lanes, one chunk each: partner half = 2 batches x 128 n / 4)
  const int s = tid - 256;
  const int pb = s >> 5;
  const int pn0 = (role ^ 1) * 128 + (s & 31) * 4;
  const int stg_base = pb * 256 + (pn0 ^ ((pb & 7) << 3));  // u16 index, + par*4096

  float c = 0.f;
  u32x2 gxc = {0, 0}, gxn = {0, 0};
  if (is_ew) {
    c = ctx[n_glob];
    gxc = *(const u32x2*)(gates + (((size_t)0 * 16 + b_glob) * 256 + n_glob) * 4);
    gxn = *(const u32x2*)(gates + (((size_t)1 * 16 + b_glob) * 256 + n_glob) * 4);
  }
  u32x4 sp = {0, 0, 0, 0};
  int tries = 64;  // fast-path spin budget; 0 => collapsed to safe-only mode
  if (is_st) sp = ld16f(exch_addr(exchF, g, role ^ 1, 1, s));  // spec for t=1

#pragma unroll 1
  for (int t = 0; t < T; ++t) {
    const int par = t & 1;
    if (is_st && t > 0) {
      asm volatile("s_waitcnt vmcnt(0)" ::: "memory");
      __builtin_amdgcn_sched_barrier(0);
      const u32 want = (u32)t;
      if (sp[3] != want) {
        const char* fa = exch_addr(exchF, g, role ^ 1, par, s);
        int kk = 0;
        while (kk < tries) {
          asm volatile("global_load_dwordx4 %0, %1, off sc0\n\ts_waitcnt vmcnt(0)"
                       : "=v"(sp) : "v"(fa) : "memory");
          if (sp[3] == want) break;
          ++kk;
        }
        if (sp[3] != want) {
          sp = spin16s(exch_addr(exchS, g, role ^ 1, par, s), want);
          tries = 0;  // partner not L2-visible: collapse to safe-only
        } else if (tries > 16) {
          tries = 16;
        }
      } else if (tries > 16) {
        tries = 16;
      }
      u32x2 wp; wp[0] = sp[0]; wp[1] = sp[1];
      *(u32x2*)&hb[par * 4096 + stg_base] = wp;
    }
    bar_lds();  // hbuf[par] complete (own half written end of prev step; partner half above)

    {  // z = Uh_own_rows . h  -> zl
      const int base = par * 4096 + l15 * 256;
      const int msk = (l15 & 7) << 3;
      u32x4 bv[8];
#pragma unroll
      for (int kt = 0; kt < 8; kt++)
        bv[kt] = *(const u32x4*)&hb[base + ((kt * 32 + lc * 8) ^ msk)];
#pragma unroll
      for (int rb = 0; rb < 4; rb++) {
        f32x4 a = {0.f, 0.f, 0.f, 0.f};
#pragma unroll
        for (int kt = 0; kt < 8; kt++) a = MFMA(uh[rb][kt], bv[kt], a);
        if (l15 < 2) {
          const int nr = sub * 64 + rb * 16 + lc * 4;
#pragma unroll
          for (int rr = 0; rr < 4; rr++) zl[(nr + rr) * 9 + q * 2 + l15] = a[rr];
        }
      }
    }
    bar_lds();  // zl ready

    if (is_st) {  // speculative issue for t+1 (mode-dependent buffer)
      if (tries > 0) sp = ld16f(exch_addr(exchF, g, role ^ 1, (t + 1) & 1, s));
      else           sp = ld16s(exch_addr(exchS, g, role ^ 1, (t + 1) & 1, s));
    }

    if (is_ew) {
      float z0 = zl[n_loc * 9 + 0 + b] + bf2f((u16)(gxc[0] & 0xFFFFu));
      float z1 = zl[n_loc * 9 + 2 + b] + bf2f((u16)(gxc[0] >> 16));
      float z2 = zl[n_loc * 9 + 4 + b] + bf2f((u16)(gxc[1] & 0xFFFFu));
      float z3 = zl[n_loc * 9 + 6 + b] + bf2f((u16)(gxc[1] >> 16));
      float fv = sigm(z0), gv = tanh_s(z1), iv = sigm(z2), ov = sigm(z3);
      c = gv * iv + c * fv;
      float hn = ov * tanh_s(c);
      gall[((size_t)b_glob * T + t) * H + n_glob] = f2bf(gv);
      // own-half h(t+1) -> hbuf[par^1]
      hb[(par ^ 1) * 4096 + b * 256 + (n_glob ^ ((b & 7) << 3))] = f2bf(hn);
      // pack 4 h -> tagged chunk -> partner (dual scope)
      int sl = lane & ~3;
      float h0 = __shfl(hn, sl + 0), h1 = __shfl(hn, sl + 1);
      float h2 = __shfl(hn, sl + 2), h3 = __shfl(hn, sl + 3);
      if ((lane & 3) == 0) {
        u32x4 cv; cv[0] = pk2(h0, h1); cv[1] = pk2(h2, h3); cv[2] = 0u; cv[3] = (u32)(t + 1);
        const int cidx = b * 32 + (n_loc >> 2);
        st16f(exch_addr(exchF, g, role, (t + 1) & 1, cidx), cv);
        st16s(exch_addr(exchS, g, role, (t + 1) & 1, cidx), cv);
      }
      gxc = gxn;
      int t2 = (t + 2 < T) ? (t + 2) : t;
      gxn = *(const u32x2*)(gates + (((size_t)t2 * 16 + b_glob) * 256 + n_glob) * 4);
    }
  }
}

// ---------------- K4: out = g_all @ Wout^T  (BM=64, BN=256, K=H; grid 128x20)
__global__ __launch_bounds__(256) void k_out(char* __restrict__ ws, float* __restrict__ out) {
  const u16* gall = (const u16*)(ws + OFF_GALL);
  const u16* Wob = (const u16*)(ws + OFF_WOUTB);
  __shared__ __align__(16) u16 As[64 * 40];
  __shared__ __align__(16) u16 Bs[256 * 40];

  const int tid = threadIdx.x;
  const int blk = blockIdx.x;
  const int m0 = (blk / 20) * 64, n0 = (blk % 20) * 256;
  const int lane = tid & 63, wv = tid >> 6;
  const int l15 = lane & 15, lc = lane >> 4;

  f32x4 acc[16];
#pragma unroll
  for (int j = 0; j < 16; j++) acc[j] = (f32x4){0.f, 0.f, 0.f, 0.f};

  u32x4 av0, av1;
  u32x4 bv0[4], bv1[4];

#define OUT_ISSUE(SFX, KS)                                                        \
  do {                                                                            \
    int k0_ = (KS) * 32;                                                          \
    {                                                                             \
      int r_ = tid >> 2, ko_ = (tid & 3) * 8;                                     \
      av##SFX = *(const u32x4*)(gall + (size_t)(m0 + r_) * H + k0_ + ko_);        \
    }                                                                             \
    _Pragma("unroll") for (int j_ = 0; j_ < 4; j_++) {                            \
      int c_ = tid + 256 * j_;                                                    \
      int n_ = c_ >> 2, ko_ = (c_ & 3) * 8;                                       \
      bv##SFX[j_] = *(const u32x4*)(Wob + (size_t)(n0 + n_) * H + k0_ + ko_);     \
    }                                                                             \
  } while (0)

#define OUT_WRITE(SFX)                                                            \
  do {                                                                            \
    {                                                                             \
      int r_ = tid >> 2, ko_ = (tid & 3) * 8;                                     \
      *(u32x4*)&As[r_ * 40 + ko_] = av##SFX;                                      \
    }                                                                             \
    _Pragma("unroll") for (int j_ = 0; j_ < 4; j_++) {                            \
      int c_ = tid + 256 * j_;                                                    \
      int n_ = c_ >> 2, ko_ = (c_ & 3) * 8;                                       \
      *(u32x4*)&Bs[n_ * 40 + ko_] = bv##SFX[j_];                                  \
    }                                                                             \
  } while (0)

  auto out_compute = [&]() {
    u32x4 a = *(const u32x4*)&As[(wv * 16 + l15) * 40 + lc * 8];
#pragma unroll
    for (int nt = 0; nt < 16; nt++) {
      u32x4 b = *(const u32x4*)&Bs[(nt * 16 + l15) * 40 + lc * 8];
      acc[nt] = MFMA(a, b, acc[nt]);
    }
  };

  constexpr int NK = 8;  // H/32
  OUT_ISSUE(0, 0);
  OUT_ISSUE(1, 1);
  for (int ks = 0; ks < NK; ks += 2) {
    __syncthreads();
    OUT_WRITE(0);
    if (ks + 2 < NK) OUT_ISSUE(0, ks + 2);
    __syncthreads();
    out_compute();
    __syncthreads();
    OUT_WRITE(1);
    if (ks + 3 < NK) OUT_ISSUE(1, ks + 3);
    __syncthreads();
    out_compute();
  }
#pragma unroll
  for (int nt = 0; nt < 16; nt++) {
    int vcol = n0 + nt * 16 + l15;
    if (vcol < V) {
#pragma unroll
      for (int r = 0; r < 4; r++) {
        int m = m0 + wv * 16 + lc * 4 + r;
        out[(size_t)m * V + vcol] = acc[nt][r];
      }
    }
  }
#undef OUT_ISSUE
#undef OUT_WRITE
}

extern "C" void kernel_launch(void* const* d_in, const int* in_sizes, int n_in,
                              void* d_out, int out_size, void* d_ws, size_t ws_size,
                              hipStream_t stream) {
  (void)in_sizes; (void)n_in; (void)out_size; (void)ws_size;  // needs ~38.7 MB of ws
  const float* x      = (const float*)d_in[0];
  const float* hidden = (const float*)d_in[1];
  const float* ctx    = (const float*)d_in[2];
  const float* E      = (const float*)d_in[3];
  const float* Wf     = (const float*)d_in[4];
  const float* Uf     = (const float*)d_in[5];
  const float* Wg     = (const float*)d_in[6];
  const float* Ug     = (const float*)d_in[7];
  const float* Wi     = (const float*)d_in[8];
  const float* Ui     = (const float*)d_in[9];
  const float* Wo     = (const float*)d_in[10];
  const float* Uo     = (const float*)d_in[11];
  const float* Wout   = (const float*)d_in[12];
  char* ws = (char*)d_ws;
  float* out = (float*)d_out;

  hipLaunchKernelGGL(k_prep, dim3(1024), dim3(256), 0, stream,
                     E, Wf, Wg, Wi, Wo, Uf, Ug, Ui, Uo, Wout, ws);
  hipLaunchKernelGGL(k_emb, dim3(M / 32), dim3(256), 0, stream, x, ws);
  hipLaunchKernelGGL(k_gates, dim3((M / 64) * 4), dim3(256), 0, stream, ws);
  hipLaunchKernelGGL(k_scan, dim3(16), dim3(512), 0, stream, hidden, ctx, ws);
  hipLaunchKernelGGL(k_out, dim3((M / 64) * 20), dim3(256), 0, stream, ws, out);
}

// Round 6
// 817.062 us; speedup vs baseline: 1.3235x; 1.3235x over previous
//
#include <hip/hip_runtime.h>
#include <stdint.h>

typedef unsigned short u16;
typedef unsigned int u32;
typedef __attribute__((ext_vector_type(8))) __bf16 bf16x8;
typedef __attribute__((ext_vector_type(4))) float f32x4;
typedef __attribute__((ext_vector_type(4))) u32 u32x4;
typedef __attribute__((ext_vector_type(2))) u32 u32x2;
typedef __attribute__((ext_vector_type(4))) int i32x4;

#define DEV __device__ __forceinline__

constexpr int V = 5000, D = 300, H = 256, BB = 16, T = 512;
constexpr int M = BB * T;      // 8192
constexpr int DP = 320;        // D padded to 20*16
constexpr int KP = 5024;       // V padded to mult of 32 (E_b k-dim)
constexpr int G4 = 1024;       // 4H
constexpr int NPAD = 5120;     // V padded to 20*256 (out n-dim)

// workspace layout (bytes, all 256-aligned). total ~38.6 MB.
constexpr size_t OFF_EB    = 0;                                   // bf16 [DP][KP]
constexpr size_t OFF_WXB   = OFF_EB    + (size_t)DP * KP * 2;     // bf16 [G4][DP]  (f,g,i,o)
constexpr size_t OFF_UHB   = OFF_WXB   + (size_t)G4 * DP * 2;     // i8 q_U [G4][H] + f32 zscale[G4]
constexpr size_t OFF_WOUTB = OFF_UHB   + (size_t)G4 * H * 2;      // bf16 [NPAD][H]
constexpr size_t OFF_GATES = OFF_WOUTB + (size_t)NPAD * H * 2;    // bf16 [T][B][256][4g]
constexpr size_t OFF_GALL  = OFF_GATES + (size_t)T * BB * G4 * 2; // bf16 [M][H], m=b*T+t
constexpr size_t OFF_EMB   = OFF_GALL  + (size_t)M * H * 2;       // f32  [M][DP]

DEV u16 f2bf(float f) {
  u32 i = __builtin_bit_cast(u32, f);
  return (u16)((i + 0x7FFFu + ((i >> 16) & 1u)) >> 16);
}
DEV float bf2f(u16 u) { return __builtin_bit_cast(float, (u32)u << 16); }
DEV f32x4 MFMA(u32x4 a, u32x4 b, f32x4 c) {
  return __builtin_amdgcn_mfma_f32_16x16x32_bf16(
      __builtin_bit_cast(bf16x8, a), __builtin_bit_cast(bf16x8, b), c, 0, 0, 0);
}
DEV i32x4 MFMA8(u32x4 a, u32x4 b, i32x4 c) {
  return __builtin_amdgcn_mfma_i32_16x16x64_i8(
      __builtin_bit_cast(i32x4, a), __builtin_bit_cast(i32x4, b), c, 0, 0, 0);
}
DEV float sigm(float x) { return 1.f / (1.f + __expf(-x)); }
DEV float tanh_s(float x) { float e = __expf(2.f * x); return 1.f - 2.f / (e + 1.f); }

// raw barrier with LDS visibility; does NOT drain vmcnt (keeps global ops in flight)
DEV void bar_lds() {
  asm volatile("s_waitcnt lgkmcnt(0)" ::: "memory");
  __builtin_amdgcn_sched_barrier(0);
  __builtin_amdgcn_s_barrier();
  __builtin_amdgcn_sched_barrier(0);
}

// ---------------- K0: weight prep (fp32 -> padded bf16)
__global__ __launch_bounds__(256) void k_prep(
    const float* __restrict__ E, const float* __restrict__ Wf, const float* __restrict__ Wg,
    const float* __restrict__ Wi, const float* __restrict__ Wo,
    const float* __restrict__ Wout, char* __restrict__ ws) {
  u16* Eb = (u16*)(ws + OFF_EB);
  u16* Wxb = (u16*)(ws + OFF_WXB);
  u16* Wob = (u16*)(ws + OFF_WOUTB);

  const int NE = DP * KP, NW = G4 * DP, NWO = NPAD * H;
  const int total = NE + NW + NWO;
  for (int i = blockIdx.x * blockDim.x + threadIdx.x; i < total; i += gridDim.x * blockDim.x) {
    int j = i;
    if (j < NE) {
      int nn = j / KP, k = j % KP;
      Eb[j] = f2bf((nn < D && k < V) ? E[(size_t)nn * V + k] : 0.f);
      continue;
    }
    j -= NE;
    if (j < NW) {
      int r = j / DP, k = j % DP;
      const float* Wp = (r < 256) ? Wf : (r < 512) ? Wg : (r < 768) ? Wi : Wo;
      Wxb[j] = f2bf((k < D) ? Wp[(size_t)(r & 255) * D + k] : 0.f);
      continue;
    }
    j -= NW;
    if (j < NWO) {
      int nn = j / H, k = j % H;
      Wob[j] = f2bf((nn < V) ? Wout[(size_t)nn * H + k] : 0.f);
      continue;
    }
  }
}

// ---------------- K0b: Uh -> int8 (per-row scale). 256 blocks x 256 thr; one wave per row.
__global__ __launch_bounds__(256) void k_prep_u(
    const float* __restrict__ Uf, const float* __restrict__ Ug,
    const float* __restrict__ Ui, const float* __restrict__ Uo, char* __restrict__ ws) {
  char* qU = ws + OFF_UHB;
  float* zsc = (float*)(ws + OFF_UHB + (size_t)G4 * H);
  const int row = blockIdx.x * 4 + (threadIdx.x >> 6);
  const int lane = threadIdx.x & 63;
  const float* Up = (row < 256) ? Uf : (row < 512) ? Ug : (row < 768) ? Ui : Uo;
  f32x4 v = *(const f32x4*)(Up + (size_t)(row & 255) * H + lane * 4);
  float m = fmaxf(fmaxf(fabsf(v[0]), fabsf(v[1])), fmaxf(fabsf(v[2]), fabsf(v[3])));
  for (int i = 1; i < 64; i <<= 1) m = fmaxf(m, __shfl_xor(m, i));
  float inv = (m > 0.f) ? 127.f / m : 0.f;
  int q0 = (int)rintf(v[0] * inv), q1 = (int)rintf(v[1] * inv);
  int q2 = (int)rintf(v[2] * inv), q3 = (int)rintf(v[3] * inv);
  q0 = max(-127, min(127, q0)); q1 = max(-127, min(127, q1));
  q2 = max(-127, min(127, q2)); q3 = max(-127, min(127, q3));
  u32 pk = (u32)(q0 & 255) | ((u32)(q1 & 255) << 8) | ((u32)(q2 & 255) << 16) |
           ((u32)(q3 & 255) << 24);
  *(u32*)(qU + (size_t)row * H + lane * 4) = pk;
  if (lane == 0) zsc[row] = m / 16129.f;  // s_n / 127^2
}

// ---------------- K1: emb = x @ E^T   (M=8192, N=DP=320, K=V; BM=32, grid=256)
__global__ __launch_bounds__(256) void k_emb(const float* __restrict__ x, char* __restrict__ ws) {
  const u16* Eb = (const u16*)(ws + OFF_EB);
  float* emb = (float*)(ws + OFF_EMB);
  __shared__ __align__(16) u16 As[32 * 40];
  __shared__ __align__(16) u16 Bs[320 * 40];

  const int tid = threadIdx.x;
  const int m0 = blockIdx.x * 32;
  const int lane = tid & 63, wv = tid >> 6;
  const int l15 = lane & 15, lc = lane >> 4;
  const int mt = wv & 1, ntb = (wv >> 1) * 10;

  f32x4 acc[10];
#pragma unroll
  for (int j = 0; j < 10; j++) acc[j] = (f32x4){0.f, 0.f, 0.f, 0.f};

  const int ar = tid >> 3, ak = (tid & 7) * 4;

  f32x4 xv0, xv1;
  u32x4 ev0[5], ev1[5];

#define EMB_ISSUE(SFX, KS)                                                        \
  do {                                                                            \
    int k0_ = (KS) * 32;                                                          \
    {                                                                             \
      size_t base_ = (size_t)(m0 + ar) * V + k0_ + ak;                            \
      if (k0_ + ak + 3 < V) {                                                     \
        xv##SFX = *(const f32x4*)(x + base_);                                     \
      } else {                                                                    \
        f32x4 t_;                                                                 \
        t_[0] = (k0_ + ak + 0 < V) ? x[base_ + 0] : 0.f;                          \
        t_[1] = (k0_ + ak + 1 < V) ? x[base_ + 1] : 0.f;                          \
        t_[2] = (k0_ + ak + 2 < V) ? x[base_ + 2] : 0.f;                          \
        t_[3] = (k0_ + ak + 3 < V) ? x[base_ + 3] : 0.f;                          \
        xv##SFX = t_;                                                             \
      }                                                                           \
    }                                                                             \
    _Pragma("unroll") for (int j_ = 0; j_ < 5; j_++) {                            \
      int cc_ = tid + 256 * j_;                                                   \
      int n_ = cc_ >> 2, ko_ = (cc_ & 3) * 8;                                     \
      ev##SFX[j_] = *(const u32x4*)(Eb + (size_t)n_ * KP + k0_ + ko_);            \
    }                                                                             \
  } while (0)

#define EMB_WRITE(SFX)                                                            \
  do {                                                                            \
    union { u16 u[4]; u32x2 v; } ua_;                                             \
    ua_.u[0] = f2bf(xv##SFX[0]); ua_.u[1] = f2bf(xv##SFX[1]);                     \
    ua_.u[2] = f2bf(xv##SFX[2]); ua_.u[3] = f2bf(xv##SFX[3]);                     \
    *(u32x2*)&As[ar * 40 + ak] = ua_.v;                                           \
    _Pragma("unroll") for (int j_ = 0; j_ < 5; j_++) {                            \
      int cc_ = tid + 256 * j_;                                                   \
      int n_ = cc_ >> 2, ko_ = (cc_ & 3) * 8;                                     \
      *(u32x4*)&Bs[n_ * 40 + ko_] = ev##SFX[j_];                                  \
    }                                                                             \
  } while (0)

  auto emb_compute = [&]() {
    u32x4 a = *(const u32x4*)&As[(mt * 16 + l15) * 40 + lc * 8];
#pragma unroll
    for (int j = 0; j < 10; j++) {
      u32x4 b = *(const u32x4*)&Bs[((ntb + j) * 16 + l15) * 40 + lc * 8];
      acc[j] = MFMA(a, b, acc[j]);
    }
  };

  constexpr int NK = 157;  // ceil(5000/32)
  EMB_ISSUE(0, 0);
  EMB_ISSUE(1, 1);
  for (int ks = 0; ks < NK; ks += 2) {
    __syncthreads();
    EMB_WRITE(0);
    if (ks + 2 < NK) EMB_ISSUE(0, ks + 2);
    __syncthreads();
    emb_compute();
    if (ks + 1 < NK) {
      __syncthreads();
      EMB_WRITE(1);
      if (ks + 3 < NK) EMB_ISSUE(1, ks + 3);
      __syncthreads();
      emb_compute();
    }
  }
#pragma unroll
  for (int j = 0; j < 10; j++) {
    int nn = (ntb + j) * 16 + l15;
    int mrow = m0 + mt * 16 + lc * 4;
#pragma unroll
    for (int r = 0; r < 4; r++) emb[(size_t)(mrow + r) * DP + nn] = acc[j][r];
  }
#undef EMB_ISSUE
#undef EMB_WRITE
}

// ---------------- K2: gates = emb @ Wx^T -> bf16 [t][b][n][4]  (BM=64,BN=256,K=DP)
__global__ __launch_bounds__(256) void k_gates(char* __restrict__ ws) {
  const float* emb = (const float*)(ws + OFF_EMB);
  const u16* Wxb = (const u16*)(ws + OFF_WXB);
  u16* gates = (u16*)(ws + OFF_GATES);
  __shared__ __align__(16) u16 As[64 * 40];
  __shared__ __align__(16) u16 Bs[256 * 40];

  const int tid = threadIdx.x;
  const int blk = blockIdx.x;
  const int m0 = (blk >> 2) * 64, n0 = (blk & 3) * 256;
  const int lane = tid & 63, wv = tid >> 6;
  const int l15 = lane & 15, lc = lane >> 4;

  f32x4 acc[16];
#pragma unroll
  for (int j = 0; j < 16; j++) acc[j] = (f32x4){0.f, 0.f, 0.f, 0.f};

  f32x4 av0[2], av1[2];
  u32x4 bv0[4], bv1[4];

#define GT_ISSUE(SFX, KS)                                                         \
  do {                                                                            \
    int k0_ = (KS) * 32;                                                          \
    _Pragma("unroll") for (int j_ = 0; j_ < 2; j_++) {                            \
      int c_ = tid + 256 * j_;                                                    \
      int r_ = c_ >> 3, ko_ = (c_ & 7) * 4;                                       \
      av##SFX[j_] = *(const f32x4*)(emb + (size_t)(m0 + r_) * DP + k0_ + ko_);    \
    }                                                                             \
    _Pragma("unroll") for (int j_ = 0; j_ < 4; j_++) {                            \
      int c_ = tid + 256 * j_;                                                    \
      int n_ = c_ >> 2, ko_ = (c_ & 3) * 8;                                       \
      bv##SFX[j_] = *(const u32x4*)(Wxb + (size_t)(n0 + n_) * DP + k0_ + ko_);    \
    }                                                                             \
  } while (0)

#define GT_WRITE(SFX)                                                             \
  do {                                                                            \
    _Pragma("unroll") for (int j_ = 0; j_ < 2; j_++) {                            \
      int c_ = tid + 256 * j_;                                                    \
      int r_ = c_ >> 3, ko_ = (c_ & 7) * 4;                                       \
      union { u16 u[4]; u32x2 v; } ua_;                                           \
      ua_.u[0] = f2bf(av##SFX[j_][0]); ua_.u[1] = f2bf(av##SFX[j_][1]);           \
      ua_.u[2] = f2bf(av##SFX[j_][2]); ua_.u[3] = f2bf(av##SFX[j_][3]);           \
      *(u32x2*)&As[r_ * 40 + ko_] = ua_.v;                                        \
    }                                                                             \
    _Pragma("unroll") for (int j_ = 0; j_ < 4; j_++) {                            \
      int c_ = tid + 256 * j_;                                                    \
      int n_ = c_ >> 2, ko_ = (c_ & 3) * 8;                                       \
      *(u32x4*)&Bs[n_ * 40 + ko_] = bv##SFX[j_];                                  \
    }                                                                             \
  } while (0)

  auto gt_compute = [&]() {
    u32x4 a = *(const u32x4*)&As[(wv * 16 + l15) * 40 + lc * 8];
#pragma unroll
    for (int nt = 0; nt < 16; nt++) {
      u32x4 b = *(const u32x4*)&Bs[(nt * 16 + l15) * 40 + lc * 8];
      acc[nt] = MFMA(a, b, acc[nt]);
    }
  };

  constexpr int NK = 10;  // DP/32
  GT_ISSUE(0, 0);
  GT_ISSUE(1, 1);
  for (int ks = 0; ks < NK; ks += 2) {
    __syncthreads();
    GT_WRITE(0);
    if (ks + 2 < NK) GT_ISSUE(0, ks + 2);
    __syncthreads();
    gt_compute();
    __syncthreads();
    GT_WRITE(1);
    if (ks + 3 < NK) GT_ISSUE(1, ks + 3);
    __syncthreads();
    gt_compute();
  }
#pragma unroll
  for (int nt = 0; nt < 16; nt++) {
#pragma unroll
    for (int r = 0; r < 4; r++) {
      int m = m0 + wv * 16 + lc * 4 + r;     // m = b*T + t
      int col = n0 + nt * 16 + l15;          // 0..1023
      int q = col >> 8, nn = col & 255;
      gates[(((size_t)(m & (T - 1)) * 16 + (m >> 9)) * 256 + nn) * 4 + q] = f2bf(acc[nt][r]);
    }
  }
#undef GT_ISSUE
#undef GT_WRITE
}

// ---------------- K3: recurrent scan, fully WG-local. 8 WGs x 512 thr; WG g owns batches
// {2g, 2g+1}. Full int8 Uh (per-row scaled) lives in VGPRs (128/lane). Per step: h (int8,
// scale 1/127; step-0 scale 4/127) -> LDS -> mfma_i32_16x16x64_i8 -> z -> gates -> h.
// No inter-WG communication at all.
__global__ __launch_bounds__(512) void k_scan(const float* __restrict__ hidden,
                                              const float* __restrict__ ctx,
                                              char* __restrict__ ws) {
  const char* qU = (const char*)(ws + OFF_UHB);
  const float* zsc = (const float*)(ws + OFF_UHB + (size_t)G4 * H);
  const u16* gates = (const u16*)(ws + OFF_GATES);
  u16* gall = (u16*)(ws + OFF_GALL);

  __shared__ __align__(16) char pq[2][2][256];  // [par][b][n] int8 h
  __shared__ __align__(16) int zl2[2][1040];    // [b][row] raw i32 z (pad 1040)

  const int tid = threadIdx.x;
  const int lane = tid & 63, wv = tid >> 6;
  const int l15 = lane & 15, lc = lane >> 4;

  // A fragments: row-tile rt = wv*8+i (rows rt*16 + l15), k-tile kt (k = kt*64 + lc*16 + j)
  u32x4 uq[8][4];
#pragma unroll
  for (int i = 0; i < 8; i++)
#pragma unroll
    for (int kt = 0; kt < 4; kt++) {
      int row = (wv * 8 + i) * 16 + l15;
      uq[i][kt] = *(const u32x4*)(qU + (size_t)row * H + kt * 64 + lc * 16);
    }

  const int b = tid >> 8, n = tid & 255;
  const int b_glob = blockIdx.x * 2 + b;
  float c = ctx[n];
  const float zs0 = zsc[n], zs1 = zsc[n + 256], zs2 = zsc[n + 512], zs3 = zsc[n + 768];
  u32x2 gxc = *(const u32x2*)(gates + (((size_t)0 * 16 + b_glob) * 256 + n) * 4);
  u32x2 gxn = *(const u32x2*)(gates + (((size_t)1 * 16 + b_glob) * 256 + n) * 4);

  {  // h(0): scale 4/127 (|h0| clamped to 4; steps >=1 have |h|<1 and use 1/127)
    float h0 = hidden[n];
    h0 = fminf(3.999f, fmaxf(-3.999f, h0));
    pq[0][b][n] = (char)(int)rintf(h0 * 31.75f);
  }
  __syncthreads();

#pragma unroll 1
  for (int t = 0; t < T; ++t) {
    const int par = t & 1;
    // B fragments: col = l15 (batch; cols 2..15 produce unused garbage), k-slice lc*16
    u32x4 bfr[4];
#pragma unroll
    for (int kt = 0; kt < 4; kt++)
      bfr[kt] = *(const u32x4*)&pq[par][l15 & 1][kt * 64 + lc * 16];

#pragma unroll
    for (int i = 0; i < 8; i++) {
      i32x4 acc = {0, 0, 0, 0};
#pragma unroll
      for (int kt = 0; kt < 4; kt++) acc = MFMA8(uq[i][kt], bfr[kt], acc);
      if (l15 < 2) *(i32x4*)&zl2[l15][(wv * 8 + i) * 16 + lc * 4] = acc;
    }
    bar_lds();  // zl2 ready

    const float hs = (t == 0) ? 4.f : 1.f;
    float z0 = (float)zl2[b][n] * zs0 * hs + bf2f((u16)(gxc[0] & 0xFFFFu));
    float z1 = (float)zl2[b][n + 256] * zs1 * hs + bf2f((u16)(gxc[0] >> 16));
    float z2 = (float)zl2[b][n + 512] * zs2 * hs + bf2f((u16)(gxc[1] & 0xFFFFu));
    float z3 = (float)zl2[b][n + 768] * zs3 * hs + bf2f((u16)(gxc[1] >> 16));
    float fv = sigm(z0), gv = tanh_s(z1), iv = sigm(z2), ov = sigm(z3);
    c = gv * iv + c * fv;
    float hn = ov * tanh_s(c);
    gall[((size_t)b_glob * T + t) * H + n] = f2bf(gv);
    pq[par ^ 1][b][n] = (char)(int)rintf(hn * 127.f);  // |hn| < 1 strictly
    gxc = gxn;
    int t2 = (t + 2 < T) ? (t + 2) : t;
    gxn = *(const u32x2*)(gates + (((size_t)t2 * 16 + b_glob) * 256 + n) * 4);
    bar_lds();  // pq[par^1] ready; zl2 reads drained before next MFMA overwrites
  }
}

// ---------------- K4: out = g_all @ Wout^T  (BM=64, BN=256, K=H; grid 128x20)
__global__ __launch_bounds__(256) void k_out(char* __restrict__ ws, float* __restrict__ out) {
  const u16* gall = (const u16*)(ws + OFF_GALL);
  const u16* Wob = (const u16*)(ws + OFF_WOUTB);
  __shared__ __align__(16) u16 As[64 * 40];
  __shared__ __align__(16) u16 Bs[256 * 40];

  const int tid = threadIdx.x;
  const int blk = blockIdx.x;
  const int m0 = (blk / 20) * 64, n0 = (blk % 20) * 256;
  const int lane = tid & 63, wv = tid >> 6;
  const int l15 = lane & 15, lc = lane >> 4;

  f32x4 acc[16];
#pragma unroll
  for (int j = 0; j < 16; j++) acc[j] = (f32x4){0.f, 0.f, 0.f, 0.f};

  u32x4 av0, av1;
  u32x4 bv0[4], bv1[4];

#define OUT_ISSUE(SFX, KS)                                                        \
  do {                                                                            \
    int k0_ = (KS) * 32;                                                          \
    {                                                                             \
      int r_ = tid >> 2, ko_ = (tid & 3) * 8;                                     \
      av##SFX = *(const u32x4*)(gall + (size_t)(m0 + r_) * H + k0_ + ko_);        \
    }                                                                             \
    _Pragma("unroll") for (int j_ = 0; j_ < 4; j_++) {                            \
      int c_ = tid + 256 * j_;                                                    \
      int n_ = c_ >> 2, ko_ = (c_ & 3) * 8;                                       \
      bv##SFX[j_] = *(const u32x4*)(Wob + (size_t)(n0 + n_) * H + k0_ + ko_);     \
    }                                                                             \
  } while (0)

#define OUT_WRITE(SFX)                                                            \
  do {                                                                            \
    {                                                                             \
      int r_ = tid >> 2, ko_ = (tid & 3) * 8;                                     \
      *(u32x4*)&As[r_ * 40 + ko_] = av##SFX;                                      \
    }                                                                             \
    _Pragma("unroll") for (int j_ = 0; j_ < 4; j_++) {                            \
      int c_ = tid + 256 * j_;                                                    \
      int n_ = c_ >> 2, ko_ = (c_ & 3) * 8;                                       \
      *(u32x4*)&Bs[n_ * 40 + ko_] = bv##SFX[j_];                                  \
    }                                                                             \
  } while (0)

  auto out_compute = [&]() {
    u32x4 a = *(const u32x4*)&As[(wv * 16 + l15) * 40 + lc * 8];
#pragma unroll
    for (int nt = 0; nt < 16; nt++) {
      u32x4 b = *(const u32x4*)&Bs[(nt * 16 + l15) * 40 + lc * 8];
      acc[nt] = MFMA(a, b, acc[nt]);
    }
  };

  constexpr int NK = 8;  // H/32
  OUT_ISSUE(0, 0);
  OUT_ISSUE(1, 1);
  for (int ks = 0; ks < NK; ks += 2) {
    __syncthreads();
    OUT_WRITE(0);
    if (ks + 2 < NK) OUT_ISSUE(0, ks + 2);
    __syncthreads();
    out_compute();
    __syncthreads();
    OUT_WRITE(1);
    if (ks + 3 < NK) OUT_ISSUE(1, ks + 3);
    __syncthreads();
    out_compute();
  }
#pragma unroll
  for (int nt = 0; nt < 16; nt++) {
    int vcol = n0 + nt * 16 + l15;
    if (vcol < V) {
#pragma unroll
      for (int r = 0; r < 4; r++) {
        int m = m0 + wv * 16 + lc * 4 + r;
        out[(size_t)m * V + vcol] = acc[nt][r];
      }
    }
  }
#undef OUT_ISSUE
#undef OUT_WRITE
}

extern "C" void kernel_launch(void* const* d_in, const int* in_sizes, int n_in,
                              void* d_out, int out_size, void* d_ws, size_t ws_size,
                              hipStream_t stream) {
  (void)in_sizes; (void)n_in; (void)out_size; (void)ws_size;  // needs ~38.6 MB of ws
  const float* x      = (const float*)d_in[0];
  const float* hidden = (const float*)d_in[1];
  const float* ctx    = (const float*)d_in[2];
  const float* E      = (const float*)d_in[3];
  const float* Wf     = (const float*)d_in[4];
  const float* Uf     = (const float*)d_in[5];
  const float* Wg     = (const float*)d_in[6];
  const float* Ug     = (const float*)d_in[7];
  const float* Wi     = (const float*)d_in[8];
  const float* Ui     = (const float*)d_in[9];
  const float* Wo     = (const float*)d_in[10];
  const float* Uo     = (const float*)d_in[11];
  const float* Wout   = (const float*)d_in[12];
  char* ws = (char*)d_ws;
  float* out = (float*)d_out;

  hipLaunchKernelGGL(k_prep, dim3(1024), dim3(256), 0, stream,
                     E, Wf, Wg, Wi, Wo, Wout, ws);
  hipLaunchKernelGGL(k_prep_u, dim3(256), dim3(256), 0, stream, Uf, Ug, Ui, Uo, ws);
  hipLaunchKernelGGL(k_emb, dim3(M / 32), dim3(256), 0, stream, x, ws);
  hipLaunchKernelGGL(k_gates, dim3((M / 64) * 4), dim3(256), 0, stream, ws);
  hipLaunchKernelGGL(k_scan, dim3(8), dim3(512), 0, stream, hidden, ctx, ws);
  hipLaunchKernelGGL(k_out, dim3((M / 64) * 20), dim3(256), 0, stream, ws, out);
}